// Round 1
// baseline (6193.428 us; speedup 1.0000x reference)
//
#include <hip/hip_runtime.h>
#include <math.h>

#define H 512
#define V 5000
#define BB 128
#define SS 64
#define TT 52

// ---------------------------------------------------------------------------
// prep: Wbig [2560,1024] = [ Wa | 0 ; W_hh | W_ih_x ],  bbig = [ba ; b_ih+b_hh]
// A2 row = [h | x] so one per-step GEMM produces qa (cols 0..511) and the
// h+x part of all 4 gates (cols 512..2559).
// ---------------------------------------------------------------------------
__global__ __launch_bounds__(256)
void prep_wbig(const float* __restrict__ Wa, const float* __restrict__ Whh,
               const float* __restrict__ Wih,
               const float* __restrict__ ba, const float* __restrict__ bih,
               const float* __restrict__ bhh,
               float* __restrict__ Wbig, float* __restrict__ bbig)
{
    const int stride = gridDim.x * blockDim.x;
    for (int idx = blockIdx.x * blockDim.x + threadIdx.x; idx < 2560 * 1024; idx += stride) {
        const int j = idx >> 10, k = idx & 1023;
        float v;
        if (j < H) v = (k < H) ? Wa[j * H + k] : 0.f;
        else {
            const int n = j - H;
            v = (k < H) ? Whh[n * H + k] : Wih[n * (2 * H) + (k - H)];
        }
        Wbig[idx] = v;
    }
    for (int j = blockIdx.x * blockDim.x + threadIdx.x; j < 2560; j += stride)
        bbig[j] = (j < H) ? ba[j] : (bih[j - H] + bhh[j - H]);
}

// ---------------------------------------------------------------------------
// Generic fp32 tiled GEMM:  C[r,n] = dot(Arow(r,:K), W[n,:K]) (+bias1+bias2)
// A rows have stride 512 (H). concat_mode: k<512 -> A (=h_prev), k>=512 ->
// emb[token(r)] (teacher-forced input). permute: store row r=t*B+b at b*T+t.
// Tile TM x 64, BK=16, 256 threads, thread tile (TM/16) x 4.
// ---------------------------------------------------------------------------
template<int TM>
__global__ __launch_bounds__(256)
void gemm_nt(const float* __restrict__ A,
             const float* __restrict__ Emb,
             const int* __restrict__ tgt, int tstep, int concat_mode,
             const float* __restrict__ W, int ldw,
             const float* __restrict__ bias1, const float* __restrict__ bias2,
             float* __restrict__ C, int ldc,
             int M, int N, int K, int permute)
{
    constexpr int RT = TM / 16;
    __shared__ float As[16][TM + 4];
    __shared__ float Ws[16][68];
    const int tid = threadIdx.x;
    const int kl  = tid & 15;
    const int rg  = tid >> 4;
    const int r0  = blockIdx.y * TM;
    const int n0  = blockIdx.x * 64;
    const int tmb = (tid >> 4) * RT;
    const int tnb = (tid & 15) * 4;

    float acc[RT][4];
#pragma unroll
    for (int i = 0; i < RT; ++i)
#pragma unroll
        for (int j = 0; j < 4; ++j) acc[i][j] = 0.f;

    int tokr[TM / 16];
    if (concat_mode) {
#pragma unroll
        for (int i = 0; i < TM / 16; ++i) {
            const int r = r0 + rg + i * 16;
            tokr[i] = (tstep == 0) ? 0 : tgt[r * TT + tstep - 1];
        }
    }

    for (int k0 = 0; k0 < K; k0 += 16) {
        const int kg = k0 + kl;
#pragma unroll
        for (int i = 0; i < TM / 16; ++i) {
            const int m = rg + i * 16;
            float v;
            if (!concat_mode || kg < H)
                v = A[(size_t)(r0 + m) * H + kg];
            else
                v = Emb[(size_t)tokr[i] * H + (kg - H)];
            As[kl][m] = v;
        }
#pragma unroll
        for (int i = 0; i < 4; ++i) {
            const int n = rg + i * 16;
            int nn = n0 + n; if (nn >= N) nn = N - 1;
            Ws[kl][n] = W[(size_t)nn * ldw + kg];
        }
        __syncthreads();
#pragma unroll
        for (int kk = 0; kk < 16; ++kk) {
            float av[RT], wv[4];
#pragma unroll
            for (int i = 0; i < RT; ++i) av[i] = As[kk][tmb + i];
#pragma unroll
            for (int j = 0; j < 4; ++j) wv[j] = Ws[kk][tnb + j];
#pragma unroll
            for (int i = 0; i < RT; ++i)
#pragma unroll
                for (int j = 0; j < 4; ++j) acc[i][j] += av[i] * wv[j];
        }
        __syncthreads();
    }

#pragma unroll
    for (int i = 0; i < RT; ++i) {
        const int r = r0 + tmb + i;
        const size_t crow = permute ? (size_t)((r & (BB - 1)) * TT + (r >> 7)) : (size_t)r;
#pragma unroll
        for (int j = 0; j < 4; ++j) {
            const int n = n0 + tnb + j;
            if (n < N) {
                float v = acc[i][j];
                if (bias1) v += bias1[n];
                if (bias2) v += bias2[n];
                C[crow * (size_t)ldc + n] = v;
            }
        }
    }
}

// ---------------------------------------------------------------------------
// Per-step attention: block b. scores[s]=tanh(qa+keys[b,s])·Va+bv, softmax,
// ctx = w·enc[b]. Also writes attention weights to the output.
// ---------------------------------------------------------------------------
__global__ __launch_bounds__(256)
void attn_step(const float* __restrict__ qg, const float* __restrict__ keys,
               const float* __restrict__ Va, const float* __restrict__ bv,
               const float* __restrict__ enc, float* __restrict__ ctx,
               float* __restrict__ attn_out, int t)
{
    __shared__ float qa_s[H], va_s[H], part[SS][4], wbuf[SS];
    const int tid = threadIdx.x;
    const int b = blockIdx.x;
    qa_s[tid]       = qg[(size_t)b * 2560 + tid];
    qa_s[tid + 256] = qg[(size_t)b * 2560 + tid + 256];
    va_s[tid] = Va[tid]; va_s[tid + 256] = Va[tid + 256];
    __syncthreads();
    const int s = tid >> 2, q = tid & 3;
    const float* kp = keys + ((size_t)b * SS + s) * H + q * 128;
    float acc = 0.f;
#pragma unroll 4
    for (int i = 0; i < 128; ++i)
        acc += tanhf(qa_s[q * 128 + i] + kp[i]) * va_s[q * 128 + i];
    part[s][q] = acc;
    __syncthreads();
    if (tid < 64) {
        float sc = part[tid][0] + part[tid][1] + part[tid][2] + part[tid][3] + bv[0];
        float m = sc;
        for (int off = 32; off; off >>= 1) m = fmaxf(m, __shfl_xor(m, off));
        const float e = expf(sc - m);
        float ssum = e;
        for (int off = 32; off; off >>= 1) ssum += __shfl_xor(ssum, off);
        const float w = e / ssum;
        wbuf[tid] = w;
        attn_out[((size_t)b * TT + t) * SS + tid] = w;
    }
    __syncthreads();
    for (int h = tid; h < H; h += 256) {
        float a2 = 0.f;
        const float* eb = enc + (size_t)b * SS * H + h;
#pragma unroll 8
        for (int s2 = 0; s2 < SS; ++s2) a2 += wbuf[s2] * eb[(size_t)s2 * H];
        ctx[(size_t)b * H + h] = a2;
    }
}

// ---------------------------------------------------------------------------
// LSTM elementwise update. gates[n] = qg[b,512+n] + gc[b,n]  (torch i,f,g,o)
// ---------------------------------------------------------------------------
__global__ __launch_bounds__(256)
void lstm_update(const float* __restrict__ qg, const float* __restrict__ gc,
                 const float* __restrict__ c0, const float* __restrict__ cprev,
                 float* __restrict__ cnew, float* __restrict__ hall_t,
                 float* __restrict__ out_h, float* __restrict__ out_c, int t)
{
    const int idx = blockIdx.x * 256 + threadIdx.x;   // < 65536
    const int b = idx >> 9, j = idx & 511;
    const float* qrow = qg + (size_t)b * 2560 + 512;
    const float* grow = gc + (size_t)b * 2048;
    const float ig = qrow[j]        + grow[j];
    const float fg = qrow[512 + j]  + grow[512 + j];
    const float gg = qrow[1024 + j] + grow[1024 + j];
    const float og = qrow[1536 + j] + grow[1536 + j];
    const float co = (t == 0) ? c0[idx] : cprev[idx];
    const float sf = 1.f / (1.f + expf(-fg));
    const float si = 1.f / (1.f + expf(-ig));
    const float so = 1.f / (1.f + expf(-og));
    const float cn = sf * co + si * tanhf(gg);
    const float hn = so * tanhf(cn);
    cnew[idx] = cn;
    hall_t[idx] = hn;
    if (out_h) { out_h[idx] = hn; out_c[idx] = cn; }
}

// ---------------------------------------------------------------------------
// In-place log-softmax over each row of 5000 logits.
// ---------------------------------------------------------------------------
__global__ __launch_bounds__(256)
void logsoftmax_rows(float* __restrict__ P)
{
    __shared__ float red[256];
    float* p = P + (size_t)blockIdx.x * V;
    const int tid = threadIdx.x;
    float m = -1e30f;
    for (int i = tid; i < V; i += 256) m = fmaxf(m, p[i]);
    red[tid] = m; __syncthreads();
    for (int sft = 128; sft; sft >>= 1) {
        if (tid < sft) red[tid] = fmaxf(red[tid], red[tid + sft]);
        __syncthreads();
    }
    m = red[0]; __syncthreads();
    float ssum = 0.f;
    for (int i = tid; i < V; i += 256) ssum += expf(p[i] - m);
    red[tid] = ssum; __syncthreads();
    for (int sft = 128; sft; sft >>= 1) {
        if (tid < sft) red[tid] += red[tid + sft];
        __syncthreads();
    }
    const float lse = m + logf(red[0]);
    for (int i = tid; i < V; i += 256) p[i] -= lse;
}

// ---------------------------------------------------------------------------
extern "C" void kernel_launch(void* const* d_in, const int* in_sizes, int n_in,
                              void* d_out, int out_size, void* d_ws, size_t ws_size,
                              hipStream_t stream)
{
    (void)in_sizes; (void)n_in; (void)out_size; (void)ws_size;
    const float* enc  = (const float*)d_in[0];
    const float* h0   = (const float*)d_in[1];
    const float* c0   = (const float*)d_in[2];
    const int*   tgt  = (const int*)  d_in[3];
    const float* emb  = (const float*)d_in[4];
    const float* Wa   = (const float*)d_in[5];
    const float* ba   = (const float*)d_in[6];
    const float* Ua   = (const float*)d_in[7];
    const float* bu   = (const float*)d_in[8];
    const float* Va   = (const float*)d_in[9];
    const float* bv   = (const float*)d_in[10];
    const float* Wih  = (const float*)d_in[11];
    const float* Whh  = (const float*)d_in[12];
    const float* bih  = (const float*)d_in[13];
    const float* bhh  = (const float*)d_in[14];
    const float* Wout = (const float*)d_in[15];
    const float* bout = (const float*)d_in[16];

    float* ws   = (float*)d_ws;
    float* keys = ws;                                  // 8192*512
    float* Wbig = keys + (size_t)BB * SS * H;          // 2560*1024
    float* bbig = Wbig + 2560 * 1024;                  // 2560
    float* qg   = bbig + 2560;                         // 128*2560
    float* gcb  = qg + BB * 2560;                      // 128*2048
    float* ctx  = gcb + BB * 2048;                     // 128*512
    float* cbuf = ctx + BB * H;                        // 2*128*512
    float* hall = cbuf + 2 * BB * H;                   // 52*128*512

    float* out    = (float*)d_out;
    float* out_h  = out + (size_t)BB * TT * V;
    float* out_c  = out_h + BB * H;
    float* out_at = out_c + BB * H;

    prep_wbig<<<dim3(2048), dim3(256), 0, stream>>>(Wa, Whh, Wih, ba, bih, bhh, Wbig, bbig);

    // keys_proj = enc @ Ua^T + bu   [8192,512]
    gemm_nt<64><<<dim3(8, 128), dim3(256), 0, stream>>>(
        enc, nullptr, nullptr, 0, 0, Ua, H, bu, nullptr, keys, H, BB * SS, H, H, 0);

    for (int t = 0; t < TT; ++t) {
        const float* hprev = (t == 0) ? h0 : (hall + (size_t)(t - 1) * BB * H);
        // qg = [h|x] @ Wbig^T + bbig   [128,2560]   (qa | gates_{h+x})
        gemm_nt<32><<<dim3(40, 4), dim3(256), 0, stream>>>(
            hprev, emb, tgt, t, 1, Wbig, 1024, bbig, nullptr, qg, 2560, BB, 2560, 1024, 0);
        attn_step<<<dim3(BB), dim3(256), 0, stream>>>(qg, keys, Va, bv, enc, ctx, out_at, t);
        // gc = ctx @ W_ih[:,512:]^T   [128,2048]
        gemm_nt<32><<<dim3(32, 4), dim3(256), 0, stream>>>(
            ctx, nullptr, nullptr, 0, 0, Wih + H, 2 * H, nullptr, nullptr, gcb, 4 * H, BB, 4 * H, H, 0);
        float* cprev = cbuf + (size_t)((t & 1) ^ 1) * BB * H;
        float* cnew  = cbuf + (size_t)(t & 1) * BB * H;
        lstm_update<<<dim3(256), dim3(256), 0, stream>>>(
            qg, gcb, c0, cprev, cnew, hall + (size_t)t * BB * H,
            (t == TT - 1) ? out_h : nullptr, (t == TT - 1) ? out_c : nullptr, t);
    }

    // logits for all (t,b): hall[6656,512] @ Wout^T + bout -> out[b,t,:] permuted
    gemm_nt<64><<<dim3(79, 104), dim3(256), 0, stream>>>(
        hall, nullptr, nullptr, 0, 0, Wout, H, bout, nullptr, out, V, TT * BB, V, H, 1);
    logsoftmax_rows<<<dim3(BB * TT), dim3(256), 0, stream>>>(out);
}